// Round 5
// baseline (228.931 us; speedup 1.0000x reference)
//
#include <hip/hip_runtime.h>
#include <hip/hip_bf16.h>
#include <cstdint>
#include <cstddef>

// ---------------------------------------------------------------------------
// TriangleTensorNetwork, restructured:
//   T[s,r,o] = sum_{x,y,z} cs[s,y,z] cr[x,r,z] co[x,y,o]   (batch-independent)
//   out[b]   = sum_s p1[b,s] * sum_{r,o} p2[b,r] p3[b,o] T[s,r,o]
// Round-5:
//   k_prep : weight transposes/casts (bf16 [n][k] layouts) + cot transpose
//   k_F    : F3[s][x][r][y] = sum_z cr[(x r),z] cs[(s y),z]  (no LDS)
//   k_proj : coalesced LDS-staged A (dbuf, 1 barrier/chunk); z=1 fuses MLP
//   k_T    : Tts[r][s][o] = sum_{x,y} F3[s][x][r][y] cot[o][(x y)]  (direct,
//            no atomics; block = (s, r-quarter), waves split x, LDS reduce)
//   k_main : C[b,s]=sum_k (p2*p3) Tts ; out[b]=dot(p1,C)  (dbuf LDS chunks)
// ---------------------------------------------------------------------------

typedef __attribute__((ext_vector_type(8))) short short8;
typedef __attribute__((ext_vector_type(4))) float f32x4;

#define DEV static __device__ __forceinline__

constexpr int NB = 16384;   // batch
constexpr int ND = 512;     // outer dim

DEV unsigned short f2bf(float f) {
    union { float f; unsigned u; } v; v.f = f;
    unsigned r = v.u + 0x7FFFu + ((v.u >> 16) & 1u);   // RNE
    return (unsigned short)(r >> 16);
}
DEV float bf2f(unsigned short h) {
    union { unsigned u; float f; } v; v.u = ((unsigned)h) << 16;
    return v.f;
}
DEV unsigned pack2(float lo, float hi) {
    return (unsigned)f2bf(lo) | ((unsigned)f2bf(hi) << 16);
}
// load 8 contiguous f32, convert to bf16x8 fragment in regs
DEV short8 ldA_f32(const float* p) {
    float4 a = *(const float4*)p, b = *(const float4*)(p + 4);
    union { unsigned u[4]; short8 s; } v;
    v.u[0] = pack2(a.x, a.y); v.u[1] = pack2(a.z, a.w);
    v.u[2] = pack2(b.x, b.y); v.u[3] = pack2(b.z, b.w);
    return v.s;
}

// ---------------------------------------------------------------------------
// K0: weight prep
// ---------------------------------------------------------------------------
__global__ void k_prep(const float* __restrict__ proj_s, const float* __restrict__ proj_r,
                       const float* __restrict__ proj_o, const float* __restrict__ cube_o,
                       const float* __restrict__ W21, const float* __restrict__ W22,
                       const float* __restrict__ W23,
                       unsigned short* __restrict__ Wp1t, unsigned short* __restrict__ Wh1,
                       unsigned short* __restrict__ Wp3t, unsigned short* __restrict__ W22b,
                       unsigned short* __restrict__ W23b, unsigned short* __restrict__ Prt,
                       unsigned short* __restrict__ cot)
{
    int i = blockIdx.x * 256 + threadIdx.x;
    if (i < 32768) { int d = i >> 6, s = i & 63; Wp1t[s * 512 + d] = f2bf(proj_s[i]); return; }
    i -= 32768;
    if (i < 32768) { Wh1[i] = f2bf(W21[i]); return; }
    i -= 32768;
    if (i < 32768) { int d = i >> 6, o = i & 63; Wp3t[o * 512 + d] = f2bf(proj_o[i]); return; }
    i -= 32768;
    if (i < 4096) { W22b[i] = f2bf(W22[i]); return; }
    i -= 4096;
    if (i < 4096) { W23b[i] = f2bf(W23[i]); return; }
    i -= 4096;
    if (i < 4096) { int k = i >> 6, n = i & 63; Prt[n * 64 + k] = f2bf(proj_r[i]); return; }
    i -= 4096;
    if (i < 262144) { int x = i >> 12, y = (i >> 6) & 63, o = i & 63;
                      cot[o * 4096 + x * 64 + y] = f2bf(cube_o[i]); return; }  // [o][(x,y)]
}

// ---------------------------------------------------------------------------
// K_F: F3[s][x][r][y] = sum_z cr[(x r),z] * cs[(s y),z]   (K=64, no LDS)
// ---------------------------------------------------------------------------
__global__ __launch_bounds__(256, 2) void k_F(
    const float* __restrict__ cr, const float* __restrict__ cs,
    unsigned short* __restrict__ F3)
{
    const int t = threadIdx.x, wid = t >> 6, l = t & 63, lr = l & 15, lk = l >> 4;
    const int wm = wid & 1, wn = wid >> 1;
    const int m0 = blockIdx.x * 128 + wm * 64, n0 = blockIdx.y * 128 + wn * 64;
    f32x4 acc[4][4] = {};
#pragma unroll
    for (int ks = 0; ks < 2; ++ks) {
        short8 av[4], bv[4];
#pragma unroll
        for (int f = 0; f < 4; ++f) {
            av[f] = ldA_f32(cr + (size_t)(m0 + f * 16 + lr) * 64 + ks * 32 + lk * 8);
            bv[f] = ldA_f32(cs + (size_t)(n0 + f * 16 + lr) * 64 + ks * 32 + lk * 8);
        }
#pragma unroll
        for (int f = 0; f < 4; ++f)
#pragma unroll
            for (int g = 0; g < 4; ++g)
                acc[f][g] = __builtin_amdgcn_mfma_f32_16x16x32_bf16(av[f], bv[g], acc[f][g], 0, 0, 0);
    }
    const int xg = m0 >> 6, sg = n0 >> 6;   // m = x*64 + r ; n = s*64 + y
#pragma unroll
    for (int f = 0; f < 4; ++f)
#pragma unroll
        for (int g = 0; g < 4; ++g)
#pragma unroll
            for (int q = 0; q < 4; ++q)
                F3[(size_t)sg * 262144 + (size_t)xg * 4096 +
                   (f * 16 + lk * 4 + q) * 64 + g * 16 + lr] = f2bf(acc[f][g][q]);
}

// ---------------------------------------------------------------------------
// K_proj: z=0: p1 ; z=2: p3 ; z=1: h1 + fused 3-stage MLP -> p2
//   64-row tile; A staged coalesced f32->bf16 into swizzled LDS, double-
//   buffered with stage-ahead regs, one barrier per 128-k chunk.
// ---------------------------------------------------------------------------
DEV void mlp_mm(const unsigned short* slab_w, const unsigned short* __restrict__ W,
                int lr, int lk, f32x4 acc[4])
{
#pragma unroll
    for (int ks = 0; ks < 2; ++ks) {
        short8 av = *(const short8*)((const char*)slab_w +
                      (lr * 128 + ((ks * 64 + lk * 16) ^ ((lr & 7) << 4))));
#pragma unroll
        for (int g = 0; g < 4; ++g) {
            short8 bv = *(const short8*)(W + (g * 16 + lr) * 64 + ks * 32 + lk * 8);
            acc[g] = __builtin_amdgcn_mfma_f32_16x16x32_bf16(av, bv, acc[g], 0, 0, 0);
        }
    }
}
DEV void store_slab(unsigned short* slab_w, int lr, int lk, const f32x4 acc[4],
                    const float* __restrict__ bias, bool relu_)
{
#pragma unroll
    for (int g = 0; g < 4; ++g) {
        float bcol = bias ? bias[g * 16 + lr] : 0.0f;
#pragma unroll
        for (int q = 0; q < 4; ++q) {
            int r = lk * 4 + q, c = g * 16 + lr;
            float v = acc[g][q] + bcol;
            if (relu_) v = fmaxf(v, 0.0f);
            *(unsigned short*)((char*)slab_w + (r * 128 + ((c * 2) ^ ((r & 7) << 4)))) = f2bf(v);
        }
    }
}

__global__ __launch_bounds__(256, 3) void k_proj(
    const float* __restrict__ in1, const float* __restrict__ in2, const float* __restrict__ in3,
    const unsigned short* __restrict__ Wp1t, const unsigned short* __restrict__ Wh1,
    const unsigned short* __restrict__ Wp3t,
    const unsigned short* __restrict__ W22b, const unsigned short* __restrict__ W23b,
    const unsigned short* __restrict__ Prt,
    const float* __restrict__ b21, const float* __restrict__ b22, const float* __restrict__ b23,
    unsigned short* __restrict__ p1bf, unsigned short* __restrict__ p2bf,
    unsigned short* __restrict__ p3bf)
{
    __shared__ __align__(16) unsigned short at[2][64 * 128];   // 2 x 16KB A tile
    __shared__ __align__(16) unsigned short slab[4][1024];     // per-wave MLP slab
    const int z = blockIdx.y;
    const float* in = (z == 0) ? in1 : (z == 1) ? in2 : in3;
    const unsigned short* Wt = (z == 0) ? Wp1t : (z == 1) ? Wh1 : Wp3t;
    const int t = threadIdx.x, wid = t >> 6, l = t & 63, lr = l & 15, lk = l >> 4;
    const int b0 = blockIdx.x * 64;

    // staging map: thread i-th load covers row srow+i*8, float4 sc4 (coalesced)
    const int srow = t >> 5, sc4 = t & 31;
    const float* sbase = in + (size_t)(b0 + srow) * ND + sc4 * 4;
    const unsigned wb0 = (unsigned)(srow * 256 + ((sc4 * 8) ^ ((srow & 7) << 4)));

    float4 rg[8];
    auto load_chunk = [&](int kc) {
#pragma unroll
        for (int i = 0; i < 8; ++i)
            rg[i] = *(const float4*)(sbase + (size_t)i * 8 * ND + kc * 128);
    };
    auto write_chunk = [&](int buf) {
        char* base = (char*)at[buf] + wb0;
#pragma unroll
        for (int i = 0; i < 8; ++i) {
            uint2 pk;
            pk.x = pack2(rg[i].x, rg[i].y);
            pk.y = pack2(rg[i].z, rg[i].w);
            *(uint2*)(base + i * 2048) = pk;
        }
    };

    load_chunk(0);
    write_chunk(0);
    __syncthreads();

    const int arow = wid * 16 + lr;
    const unsigned rsw = (unsigned)((arow & 7) << 4);
    f32x4 acc[4] = {};
    for (int kc = 0; kc < 4; ++kc) {
        if (kc < 3) load_chunk(kc + 1);
        const char* rb = (const char*)at[kc & 1] + arow * 256;
#pragma unroll
        for (int ks = 0; ks < 4; ++ks) {
            short8 av = *(const short8*)(rb + ((unsigned)(ks * 64 + lk * 16) ^ rsw));
#pragma unroll
            for (int g = 0; g < 4; ++g) {
                short8 bv = *(const short8*)(Wt + (size_t)(g * 16 + lr) * 512 + kc * 128 + ks * 32 + lk * 8);
                acc[g] = __builtin_amdgcn_mfma_f32_16x16x32_bf16(av, bv, acc[g], 0, 0, 0);
            }
        }
        if (kc < 3) write_chunk((kc + 1) & 1);
        __syncthreads();
    }

    const int rbase = b0 + wid * 16;
    if (z != 1) {
        unsigned short* outp = (z == 0) ? p1bf : p3bf;
#pragma unroll
        for (int g = 0; g < 4; ++g)
#pragma unroll
            for (int q = 0; q < 4; ++q)
                outp[(size_t)(rbase + lk * 4 + q) * 64 + g * 16 + lr] = f2bf(acc[g][q]);
    } else {
        unsigned short* slw = slab[wid];
        store_slab(slw, lr, lk, acc, b21, true);        // h1 = relu(.+b21)
        __syncthreads();                                // full drain (vm+lgkm)
        f32x4 a2[4] = {}; mlp_mm(slw, W22b, lr, lk, a2);
        store_slab(slw, lr, lk, a2, b22, true);         // h2 = relu(.+b22)
        __syncthreads();
        f32x4 a3[4] = {}; mlp_mm(slw, W23b, lr, lk, a3);
        store_slab(slw, lr, lk, a3, b23, false);        // h3 = .+b23
        __syncthreads();
        f32x4 a4[4] = {}; mlp_mm(slw, Prt, lr, lk, a4); // p2 = h3 @ proj_r
#pragma unroll
        for (int g = 0; g < 4; ++g)
#pragma unroll
            for (int q = 0; q < 4; ++q)
                p2bf[(size_t)(rbase + lk * 4 + q) * 64 + g * 16 + lr] = f2bf(a4[g][q]);
    }
}

// ---------------------------------------------------------------------------
// K_T: block (s, rq) -> final Tts[r=rq*16+.., s, o] = sum_{x,y} F3[s][x][r][y]
//      * cot[o][(x y)].  Waves split x (16 each), LDS reduce, direct bf16 out.
// ---------------------------------------------------------------------------
__global__ __launch_bounds__(256, 1) void k_T(
    const unsigned short* __restrict__ F3, const unsigned short* __restrict__ cot,
    unsigned short* __restrict__ Tts)
{
    __shared__ float red[4][1024];
    const int s = blockIdx.x, rq = blockIdx.y;
    const int t = threadIdx.x, wid = t >> 6, l = t & 63, lr = l & 15, lk = l >> 4;
    const unsigned short* Fs = F3 + (size_t)s * 262144 + (rq * 16 + lr) * 64;
    f32x4 acc[4] = {};
#pragma unroll
    for (int xi = 0; xi < 16; ++xi) {
        int x = wid * 16 + xi;
#pragma unroll
        for (int ks = 0; ks < 2; ++ks) {
            short8 av = *(const short8*)(Fs + (size_t)x * 4096 + ks * 32 + lk * 8);
#pragma unroll
            for (int g = 0; g < 4; ++g) {
                short8 bv = *(const short8*)(cot + (size_t)(g * 16 + lr) * 4096 + x * 64 + ks * 32 + lk * 8);
                acc[g] = __builtin_amdgcn_mfma_f32_16x16x32_bf16(av, bv, acc[g], 0, 0, 0);
            }
        }
    }
#pragma unroll
    for (int g = 0; g < 4; ++g)
#pragma unroll
        for (int q = 0; q < 4; ++q)
            red[wid][(lk * 4 + q) * 64 + g * 16 + lr] = acc[g][q];
    __syncthreads();
#pragma unroll
    for (int i = 0; i < 4; ++i) {
        int idx = t + i * 256;                  // idx = r_loc*64 + o
        int r_loc = idx >> 6, o = idx & 63;
        float v = red[0][idx] + red[1][idx] + red[2][idx] + red[3][idx];
        Tts[(size_t)(rq * 16 + r_loc) * 4096 + s * 64 + o] = f2bf(v);
    }
}

// ---------------------------------------------------------------------------
// K_main: C[b,s] = sum_k (p2[b,r]*p3[b,o]) Tts[k][s][.] ; out[b] += dot(p1,C)
//   64-row blocks, grid (256, 4 kh); dbuf LDS chunk (swizzled), 1 barrier/kc
// ---------------------------------------------------------------------------
__global__ __launch_bounds__(256, 4) void k_main(
    const unsigned short* __restrict__ p1bf, const unsigned short* __restrict__ p2bf,
    const unsigned short* __restrict__ p3bf, const unsigned short* __restrict__ Tts,
    float* __restrict__ out)
{
    __shared__ __align__(16) unsigned short tb[2][4096];   // two 8KB chunks [s][k64] swizzled
    const int t = threadIdx.x, wid = t >> 6, l = t & 63, lr = l & 15, lk = l >> 4;
    const int b0 = blockIdx.x * 64, kh = blockIdx.y;       // kh in [0,4): 16 chunks each
    const int row = b0 + wid * 16 + lr;

    // p3 fragment values (f32) and p2 quarter-row (bf16x8 regs)
    float p3v[2][8];
#pragma unroll
    for (int ks = 0; ks < 2; ++ks) {
        short8 v = *(const short8*)(p3bf + (size_t)row * 64 + ks * 32 + lk * 8);
#pragma unroll
        for (int j = 0; j < 8; ++j) p3v[ks][j] = bf2f((unsigned short)v[j]);
    }
    short8 p2r[2];
#pragma unroll
    for (int i = 0; i < 2; ++i)
        p2r[i] = *(const short8*)(p2bf + (size_t)row * 64 + kh * 16 + i * 8);

    // staging geometry: thread covers bytes [t*32, t*32+32) of the 8KB chunk
    const int srow_st = t >> 2, kb_st = (t & 3) * 32;
    const unsigned swz0 = (unsigned)(kb_st ^ ((srow_st & 7) << 4));
    const unsigned swz1 = (unsigned)((kb_st + 16) ^ ((srow_st & 7) << 4));

    // prologue: stage chunk 0
    {
        const uint4* src = (const uint4*)((const char*)(Tts + (size_t)(kh * 16) * 4096) + t * 32);
        uint4 v0 = src[0], v1 = src[1];
        char* dst = (char*)tb[0] + srow_st * 128;
        *(uint4*)(dst + swz0) = v0;
        *(uint4*)(dst + swz1) = v1;
        __syncthreads();
    }

    f32x4 acc[4] = {};
#pragma unroll
    for (int i = 0; i < 16; ++i) {
        const int buf = i & 1;
        // 1) issue next-chunk loads early (hide latency under MFMA)
        uint4 n0 = {}, n1 = {};
        if (i < 15) {
            const uint4* src = (const uint4*)((const char*)(Tts + (size_t)(kh * 16 + i + 1) * 4096) + t * 32);
            n0 = src[0]; n1 = src[1];
        }
        // 2) compute current chunk
        float p2s = bf2f((unsigned short)p2r[i >> 3][i & 7]);
#pragma unroll
        for (int ks = 0; ks < 2; ++ks) {
            union { unsigned u[4]; short8 s; } a;
#pragma unroll
            for (int jj = 0; jj < 4; ++jj)
                a.u[jj] = pack2(p2s * p3v[ks][jj * 2], p2s * p3v[ks][jj * 2 + 1]);
#pragma unroll
            for (int g = 0; g < 4; ++g) {
                int n = g * 16 + lr;
                short8 bv = *(const short8*)((const char*)tb[buf] +
                              (n * 128 + ((ks * 64 + lk * 16) ^ ((n & 7) << 4))));
                acc[g] = __builtin_amdgcn_mfma_f32_16x16x32_bf16(a.s, bv, acc[g], 0, 0, 0);
            }
        }
        // 3) write next chunk into other buffer, one barrier per iteration
        if (i < 15) {
            char* dst = (char*)tb[buf ^ 1] + srow_st * 128;
            *(uint4*)(dst + swz0) = n0;
            *(uint4*)(dst + swz1) = n1;
            __syncthreads();
        }
    }

    // epilogue: out[b] += sum_s C[b,s] * p1[b,s]
    float rsum[4] = {};
#pragma unroll
    for (int g = 0; g < 4; ++g)
#pragma unroll
        for (int q = 0; q < 4; ++q) {
            int r = b0 + wid * 16 + lk * 4 + q, c = g * 16 + lr;
            rsum[q] += acc[g][q] * bf2f(p1bf[(size_t)r * 64 + c]);
        }
#pragma unroll
    for (int q = 0; q < 4; ++q) {
        float v = rsum[q];
        v += __shfl_xor(v, 1);
        v += __shfl_xor(v, 2);
        v += __shfl_xor(v, 4);
        v += __shfl_xor(v, 8);
        if (lr == 0)
            atomicAdd(&out[b0 + wid * 16 + lk * 4 + q], v);
    }
}

// ---------------------------------------------------------------------------
extern "C" void kernel_launch(void* const* d_in, const int* in_sizes, int n_in,
                              void* d_out, int out_size, void* d_ws, size_t ws_size,
                              hipStream_t stream)
{
    const float* in1    = (const float*)d_in[0];
    const float* in2    = (const float*)d_in[1];
    const float* in3    = (const float*)d_in[2];
    const float* proj_s = (const float*)d_in[3];
    const float* proj_r = (const float*)d_in[4];
    const float* proj_o = (const float*)d_in[5];
    const float* cube_s = (const float*)d_in[6];
    const float* cube_r = (const float*)d_in[7];
    const float* cube_o = (const float*)d_in[8];
    const float* W21    = (const float*)d_in[9];
    const float* b21    = (const float*)d_in[10];
    const float* W22    = (const float*)d_in[11];
    const float* b22    = (const float*)d_in[12];
    const float* W23    = (const float*)d_in[13];
    const float* b23    = (const float*)d_in[14];
    float* out = (float*)d_out;

    char* ws = (char*)d_ws;
    size_t off = 0;
    auto alloc = [&](size_t bytes) -> char* {
        char* p = ws + off;
        off += (bytes + 255) & ~(size_t)255;
        return p;
    };
    unsigned short* p1bf = (unsigned short*)alloc((size_t)NB * 64 * 2);
    unsigned short* p2bf = (unsigned short*)alloc((size_t)NB * 64 * 2);
    unsigned short* p3bf = (unsigned short*)alloc((size_t)NB * 64 * 2);
    unsigned short* Wp1t = (unsigned short*)alloc(64 * 512 * 2);
    unsigned short* Wh1  = (unsigned short*)alloc(64 * 512 * 2);
    unsigned short* Wp3t = (unsigned short*)alloc(64 * 512 * 2);
    unsigned short* W22b = (unsigned short*)alloc(64 * 64 * 2);
    unsigned short* W23b = (unsigned short*)alloc(64 * 64 * 2);
    unsigned short* Prt  = (unsigned short*)alloc(64 * 64 * 2);
    unsigned short* cot  = (unsigned short*)alloc(262144 * 2);
    unsigned short* Tts  = (unsigned short*)alloc(262144 * 2);
    unsigned short* F3   = (unsigned short*)alloc((size_t)4096 * 4096 * 2); // 32 MB

    hipMemsetAsync(d_out, 0, (size_t)out_size * sizeof(float), stream);

    k_prep<<<1456, 256, 0, stream>>>(proj_s, proj_r, proj_o, cube_o, W21, W22, W23,
                                     Wp1t, Wh1, Wp3t, W22b, W23b, Prt, cot);
    k_F<<<dim3(32, 32), 256, 0, stream>>>(cube_r, cube_s, F3);
    k_proj<<<dim3(NB / 64, 3), 256, 0, stream>>>(in1, in2, in3, Wp1t, Wh1, Wp3t,
                                                 W22b, W23b, Prt, b21, b22, b23,
                                                 p1bf, p2bf, p3bf);
    k_T<<<dim3(64, 4), 256, 0, stream>>>(F3, cot, Tts);
    k_main<<<dim3(NB / 64, 4), 256, 0, stream>>>(p1bf, p2bf, p3bf, Tts, out);
}